// Round 1
// baseline (3280.779 us; speedup 1.0000x reference)
//
#include <hip/hip_runtime.h>
#include <stdint.h>

// DecoderRNN: B=256, NSTEPS=128, I=128, H=1024, V=1024, teacher-forced GRU.
// Strategy:
//   precompute: E = relu(embed_w)@W_ih[:,:H]^T  (vocab table, MFMA bf16)
//               Zih = z@W_ih[:,H:]^T + b_ih ; Zout = z@out_w[:,H:]^T + out_b
//               h0 = z@z2h_w^T + z2h_b
//   per step t (129 fused launches):
//               GRU blocks:  gh = h_{t-1}@W_hh^T (bf16 MFMA, 3-gate tiles) ->
//                            gates epilogue -> h_t     (skipped at t=128)
//               OUT blocks:  o_{t-1} = h_{t-1}@out_w[:,:H]^T + Zout (t>=1)

#define Hh 1024
#define Ii 128
#define Bb 256
#define Vv 1024
#define NSTEP 128
#define BK 64
#define KIT (Hh / BK) /* 16 */

typedef unsigned short u16;
typedef unsigned int u32;
typedef __attribute__((ext_vector_type(8))) short bf16x8;
typedef __attribute__((ext_vector_type(4))) float f32x4;

typedef __attribute__((address_space(3))) void lds_void;
typedef const __attribute__((address_space(1))) void glb_void;
#define GLD16(g, l) __builtin_amdgcn_global_load_lds((glb_void*)(g), (lds_void*)(l), 16, 0, 0)

__device__ __forceinline__ u16 f2bf(float f) {
    u32 u = __float_as_uint(f);
    u = (u + 0x7FFFu + ((u >> 16) & 1u)) >> 16;
    return (u16)u;
}

// ---- elementwise fp32 -> bf16 cast (K fixed = 1024 columns) ----------------
__global__ void cast_k(const float* __restrict__ src, int ld, int off, int relu,
                       u16* __restrict__ dst, int n) {
    for (int i = blockIdx.x * blockDim.x + threadIdx.x; i < n; i += gridDim.x * blockDim.x) {
        int row = i >> 10, col = i & 1023;
        float v = src[(long)row * ld + off + col];
        if (relu) v = fmaxf(v, 0.f);
        dst[i] = f2bf(v);
    }
}

// ---- small fp32 GEMM: C[b][n] = z[b]·W[n, off:off+128] + bias[n] ----------
// grid = N blocks, block = 256 threads (one per batch row b)
__global__ void smallgemm_k(const float* __restrict__ z, const float* __restrict__ W,
                            int ldw, int off, const float* __restrict__ bias,
                            float* __restrict__ C, u16* __restrict__ Cbf, int N) {
    int n = blockIdx.x;
    int b = threadIdx.x;
    float acc = bias[n];
    const float* zr = z + b * Ii;
    const float* wr = W + (long)n * ldw + off;
#pragma unroll 8
    for (int k = 0; k < Ii; ++k) acc += zr[k] * wr[k];
    C[b * N + n] = acc;
    if (Cbf) Cbf[b * N + n] = f2bf(acc);
}

// ---- E table GEMM: E[v][n] = relu(embed)[v]·Wihh[n]  (M=1024,N=3072,K=1024)
// tile 32 rows x 128 cols, 4 waves (32 cols each), BK=64, depth-2 pipeline
__global__ __launch_bounds__(256) void egemm_k(const u16* __restrict__ A,
                                               const u16* __restrict__ W,
                                               float* __restrict__ C) {
    __shared__ __align__(16) u16 lds[2][160 * 64]; // rows 0..31 = A, 32..159 = W
    int tid = threadIdx.x, lane = tid & 63, wv = tid >> 6;
    int r0 = (blockIdx.x & 31) * 32;
    int n0 = (blockIdx.x >> 5) * 128;

    f32x4 acc[2][2];
#pragma unroll
    for (int m = 0; m < 2; ++m)
#pragma unroll
        for (int n = 0; n < 2; ++n) acc[m][n] = (f32x4){0.f, 0.f, 0.f, 0.f};

    auto stage = [&](int k0, int bufi) {
#pragma unroll
        for (int r = 0; r < 5; ++r) {
            int L = r * 256 + tid;
            int row = L >> 3;
            int c4 = (L & 7) ^ (row & 7); // inverse-swizzled global source (rule #21)
            const u16* src = (row < 32)
                                 ? A + (long)(r0 + row) * 1024 + k0 + c4 * 8
                                 : W + (long)(n0 + row - 32) * 1024 + k0 + c4 * 8;
            GLD16(src, &lds[bufi][L * 8]);
        }
    };
    stage(0, 0);
    stage(BK, 1);
    for (int it = 0; it < KIT; ++it) {
        if (it < KIT - 1) asm volatile("s_waitcnt vmcnt(5)" ::: "memory");
        else              asm volatile("s_waitcnt vmcnt(0)" ::: "memory");
        __builtin_amdgcn_s_barrier();
        const char* base = (const char*)&lds[it & 1][0];
        bf16x8 af[2][2], bfr[2][2];
#pragma unroll
        for (int ks = 0; ks < 2; ++ks)
#pragma unroll
            for (int q = 0; q < 2; ++q) {
                int kb = ks * 64 + ((lane >> 4) << 4);
                int rowa = q * 16 + (lane & 15);
                af[ks][q] = *(const bf16x8*)(base + rowa * 128 + (kb ^ ((rowa & 7) << 4)));
                int rowb = 32 + wv * 32 + q * 16 + (lane & 15);
                bfr[ks][q] = *(const bf16x8*)(base + rowb * 128 + (kb ^ ((rowb & 7) << 4)));
            }
#pragma unroll
        for (int ks = 0; ks < 2; ++ks)
#pragma unroll
            for (int m = 0; m < 2; ++m)
#pragma unroll
                for (int n = 0; n < 2; ++n)
                    acc[m][n] = __builtin_amdgcn_mfma_f32_16x16x32_bf16(af[ks][m], bfr[ks][n],
                                                                        acc[m][n], 0, 0, 0);
        asm volatile("s_waitcnt lgkmcnt(0)" ::: "memory");
        __builtin_amdgcn_s_barrier();
        if (it + 2 < KIT) stage((it + 2) * BK, it & 1);
    }
#pragma unroll
    for (int m = 0; m < 2; ++m)
#pragma unroll
        for (int n = 0; n < 2; ++n)
#pragma unroll
            for (int r = 0; r < 4; ++r) {
                int row = r0 + m * 16 + ((lane >> 4) << 2) + r;
                int col = n0 + wv * 32 + n * 16 + (lane & 15);
                C[(long)row * 3072 + col] = acc[m][n][r];
            }
}

// ---- fused per-step kernel ------------------------------------------------
// blocks 0..63: GRU (h_{t-1} -> h_t), blocks 64..127: OUT (h_{t-1} -> o_{t-1})
__global__ __launch_bounds__(256) void step_k(
    const u16* __restrict__ Whh,   // [3072][1024] bf16
    const u16* __restrict__ Wout,  // [1024][1024] bf16 (out_w[:, :H])
    const float* __restrict__ E,   // [1024][3072]
    const float* __restrict__ Zih, // [256][3072]
    const float* __restrict__ Zout,// [256][1024]
    const float* __restrict__ bhh, // [3072]
    const int* __restrict__ toks,  // [128][256]
    const float* __restrict__ hpf, const u16* __restrict__ hpb, // h_{t-1}
    float* __restrict__ hnf, u16* __restrict__ hnb,             // h_t
    float* __restrict__ out, int t) {
    __shared__ __align__(16) u16 lds[2][416 * 64]; // 104 KB (GRU); OUT uses first 160 rows
    int bid = blockIdx.x;
    int tid = threadIdx.x, lane = tid & 63, wv = tid >> 6;
    bool isgru = bid < 64;
    if (isgru && t == NSTEP) return;
    if (!isgru && t == 0) return;
    int sb = isgru ? bid : bid - 64;
    int r0 = (sb >> 3) * 32;   // batch-row tile
    int cb = (sb & 7) * 128;   // output-col tile

    if (isgru) {
        f32x4 acc[2][2][3];
#pragma unroll
        for (int m = 0; m < 2; ++m)
#pragma unroll
            for (int n = 0; n < 2; ++n)
#pragma unroll
                for (int g = 0; g < 3; ++g) acc[m][n][g] = (f32x4){0.f, 0.f, 0.f, 0.f};

        auto stage = [&](int k0, int bufi) {
#pragma unroll
            for (int r = 0; r < 13; ++r) {
                int L = r * 256 + tid;
                int row = L >> 3;
                int c4 = (L & 7) ^ (row & 7);
                const u16* src;
                if (row < 32) src = hpb + (long)(r0 + row) * 1024 + k0 + c4 * 8;
                else {
                    int rb = row - 32;
                    src = Whh + (long)((rb >> 7) * 1024 + cb + (rb & 127)) * 1024 + k0 + c4 * 8;
                }
                GLD16(src, &lds[bufi][L * 8]);
            }
        };
        stage(0, 0);
        stage(BK, 1);
        for (int it = 0; it < KIT; ++it) {
            if (it < KIT - 1) asm volatile("s_waitcnt vmcnt(13)" ::: "memory");
            else              asm volatile("s_waitcnt vmcnt(0)" ::: "memory");
            __builtin_amdgcn_s_barrier();
            const char* base = (const char*)&lds[it & 1][0];
            bf16x8 af[2][2];
#pragma unroll
            for (int ks = 0; ks < 2; ++ks)
#pragma unroll
                for (int m = 0; m < 2; ++m) {
                    int row = m * 16 + (lane & 15);
                    int kb = ks * 64 + ((lane >> 4) << 4);
                    af[ks][m] = *(const bf16x8*)(base + row * 128 + (kb ^ ((row & 7) << 4)));
                }
#pragma unroll
            for (int g = 0; g < 3; ++g)
#pragma unroll
                for (int ks = 0; ks < 2; ++ks)
#pragma unroll
                    for (int ni = 0; ni < 2; ++ni) {
                        int row = 32 + g * 128 + wv * 32 + ni * 16 + (lane & 15);
                        int kb = ks * 64 + ((lane >> 4) << 4);
                        bf16x8 bfrag =
                            *(const bf16x8*)(base + row * 128 + (kb ^ ((row & 7) << 4)));
#pragma unroll
                        for (int m = 0; m < 2; ++m)
                            acc[m][ni][g] = __builtin_amdgcn_mfma_f32_16x16x32_bf16(
                                af[ks][m], bfrag, acc[m][ni][g], 0, 0, 0);
                    }
            asm volatile("s_waitcnt lgkmcnt(0)" ::: "memory");
            __builtin_amdgcn_s_barrier();
            if (it + 2 < KIT) stage((it + 2) * BK, it & 1);
        }
        // gates epilogue -> h_t
#pragma unroll
        for (int m = 0; m < 2; ++m)
#pragma unroll
            for (int ni = 0; ni < 2; ++ni)
#pragma unroll
                for (int r = 0; r < 4; ++r) {
                    int b = r0 + m * 16 + ((lane >> 4) << 2) + r;
                    int j = cb + wv * 32 + ni * 16 + (lane & 15);
                    int tok = (t == 0) ? 0 : toks[(t - 1) * Bb + b];
                    float gir = E[(long)tok * 3072 + j] + Zih[(long)b * 3072 + j];
                    float giz = E[(long)tok * 3072 + 1024 + j] + Zih[(long)b * 3072 + 1024 + j];
                    float gin = E[(long)tok * 3072 + 2048 + j] + Zih[(long)b * 3072 + 2048 + j];
                    float ghr = acc[m][ni][0][r] + bhh[j];
                    float ghz = acc[m][ni][1][r] + bhh[1024 + j];
                    float ghn = acc[m][ni][2][r] + bhh[2048 + j];
                    float rg = 1.f / (1.f + expf(-(gir + ghr)));
                    float zg = 1.f / (1.f + expf(-(giz + ghz)));
                    float nn = tanhf(gin + rg * ghn);
                    float hp = hpf[b * 1024 + j];
                    float hv = (1.f - zg) * nn + zg * hp;
                    hnf[b * 1024 + j] = hv;
                    hnb[b * 1024 + j] = f2bf(hv);
                }
    } else {
        f32x4 acc[2][2];
#pragma unroll
        for (int m = 0; m < 2; ++m)
#pragma unroll
            for (int n = 0; n < 2; ++n) acc[m][n] = (f32x4){0.f, 0.f, 0.f, 0.f};

        auto stage = [&](int k0, int bufi) {
#pragma unroll
            for (int r = 0; r < 5; ++r) {
                int L = r * 256 + tid;
                int row = L >> 3;
                int c4 = (L & 7) ^ (row & 7);
                const u16* src = (row < 32)
                                     ? hpb + (long)(r0 + row) * 1024 + k0 + c4 * 8
                                     : Wout + (long)(cb + row - 32) * 1024 + k0 + c4 * 8;
                GLD16(src, &lds[bufi][L * 8]);
            }
        };
        stage(0, 0);
        stage(BK, 1);
        for (int it = 0; it < KIT; ++it) {
            if (it < KIT - 1) asm volatile("s_waitcnt vmcnt(5)" ::: "memory");
            else              asm volatile("s_waitcnt vmcnt(0)" ::: "memory");
            __builtin_amdgcn_s_barrier();
            const char* base = (const char*)&lds[it & 1][0];
            bf16x8 af[2][2], bfr[2][2];
#pragma unroll
            for (int ks = 0; ks < 2; ++ks)
#pragma unroll
                for (int q = 0; q < 2; ++q) {
                    int kb = ks * 64 + ((lane >> 4) << 4);
                    int rowa = q * 16 + (lane & 15);
                    af[ks][q] = *(const bf16x8*)(base + rowa * 128 + (kb ^ ((rowa & 7) << 4)));
                    int rowb = 32 + wv * 32 + q * 16 + (lane & 15);
                    bfr[ks][q] = *(const bf16x8*)(base + rowb * 128 + (kb ^ ((rowb & 7) << 4)));
                }
#pragma unroll
            for (int ks = 0; ks < 2; ++ks)
#pragma unroll
                for (int m = 0; m < 2; ++m)
#pragma unroll
                    for (int n = 0; n < 2; ++n)
                        acc[m][n] = __builtin_amdgcn_mfma_f32_16x16x32_bf16(
                            af[ks][m], bfr[ks][n], acc[m][n], 0, 0, 0);
            asm volatile("s_waitcnt lgkmcnt(0)" ::: "memory");
            __builtin_amdgcn_s_barrier();
            if (it + 2 < KIT) stage((it + 2) * BK, it & 1);
        }
#pragma unroll
        for (int m = 0; m < 2; ++m)
#pragma unroll
            for (int n = 0; n < 2; ++n)
#pragma unroll
                for (int r = 0; r < 4; ++r) {
                    int b = r0 + m * 16 + ((lane >> 4) << 2) + r;
                    int v = cb + wv * 32 + n * 16 + (lane & 15);
                    out[(long)b * (NSTEP * Vv) + (long)(t - 1) * Vv + v] =
                        acc[m][n][r] + Zout[b * 1024 + v];
                }
    }
}

extern "C" void kernel_launch(void* const* d_in, const int* in_sizes, int n_in,
                              void* d_out, int out_size, void* d_ws, size_t ws_size,
                              hipStream_t stream) {
    const float* z = (const float*)d_in[0];
    const int* toks = (const int*)d_in[1];
    const float* embed_w = (const float*)d_in[3];
    const float* z2h_w = (const float*)d_in[4];
    const float* z2h_b = (const float*)d_in[5];
    const float* w_ih = (const float*)d_in[6];
    const float* b_ih = (const float*)d_in[7];
    const float* w_hh = (const float*)d_in[8];
    const float* b_hh = (const float*)d_in[9];
    const float* out_w = (const float*)d_in[10];
    const float* out_b = (const float*)d_in[11];
    float* out = (float*)d_out;

    char* ws = (char*)d_ws;
    size_t off = 0;
    auto alloc = [&](size_t bytes) {
        char* p = ws + off;
        off += (bytes + 255) & ~(size_t)255;
        return p;
    };
    u16* Whh_bf = (u16*)alloc(3072ull * 1024 * 2);
    u16* Wout_bf = (u16*)alloc(1024ull * 1024 * 2);
    u16* Wihh_bf = (u16*)alloc(3072ull * 1024 * 2);
    u16* Emb_bf = (u16*)alloc(1024ull * 1024 * 2);
    float* E = (float*)alloc(1024ull * 3072 * 4);
    float* Zih = (float*)alloc(256ull * 3072 * 4);
    float* Zout = (float*)alloc(256ull * 1024 * 4);
    float* hf = (float*)alloc(2ull * 256 * 1024 * 4);
    u16* hb = (u16*)alloc(2ull * 256 * 1024 * 2);
    // total ws use ~36.7 MB

    cast_k<<<2048, 256, 0, stream>>>(w_hh, 1024, 0, 0, Whh_bf, 3072 * 1024);
    cast_k<<<2048, 256, 0, stream>>>(out_w, 1152, 0, 0, Wout_bf, 1024 * 1024);
    cast_k<<<2048, 256, 0, stream>>>(w_ih, 1152, 0, 0, Wihh_bf, 3072 * 1024);
    cast_k<<<1024, 256, 0, stream>>>(embed_w, 1024, 0, 1, Emb_bf, 1024 * 1024);
    smallgemm_k<<<1024, 256, 0, stream>>>(z, z2h_w, 128, 0, z2h_b, hf, hb, 1024);
    smallgemm_k<<<3072, 256, 0, stream>>>(z, w_ih, 1152, 1024, b_ih, Zih, nullptr, 3072);
    smallgemm_k<<<1024, 256, 0, stream>>>(z, out_w, 1152, 1024, out_b, Zout, nullptr, 1024);
    egemm_k<<<768, 256, 0, stream>>>(Emb_bf, Wihh_bf, E);

    for (int t = 0; t <= NSTEP; ++t) {
        int cur = t & 1;
        step_k<<<128, 256, 0, stream>>>(Whh_bf, Wout_bf, E, Zih, Zout, b_hh, toks,
                                        hf + (size_t)cur * 256 * 1024,
                                        hb + (size_t)cur * 256 * 1024,
                                        hf + (size_t)(cur ^ 1) * 256 * 1024,
                                        hb + (size_t)(cur ^ 1) * 256 * 1024, out, t);
    }
}

// Round 2
// 2186.199 us; speedup vs baseline: 1.5007x; 1.5007x over previous
//
#include <hip/hip_runtime.h>
#include <stdint.h>

// DecoderRNN: B=256, NSTEPS=128, I=128, H=1024, V=1024, teacher-forced GRU.
//   precompute: E = relu(embed_w)@W_ih[:,:H]^T  (vocab table, MFMA bf16)
//               Zih = z@W_ih[:,H:]^T + b_ih ; Zout = z@out_w[:,H:]^T + out_b
//               h0 = z@z2h_w^T + z2h_b
//   per step t (129 fused launches, grid 256):
//     blocks 0..127   GRU: gh = h_{t-1}@W_hh^T (32r x 64j x 3 gates, BK=128,
//                          8 iters, depth-2 pipeline) -> gates -> h_t
//     blocks 128..255 OUT: o_{t-1} = h_{t-1}@out_w[:,:H]^T + Zout (32r x 64v)

#define Hh 1024
#define Ii 128
#define Bb 256
#define Vv 1024
#define NSTEP 128
#define BK 128
#define KIT (Hh / BK) /* 8 */

typedef unsigned short u16;
typedef unsigned int u32;
typedef __attribute__((ext_vector_type(8))) short bf16x8;
typedef __attribute__((ext_vector_type(4))) float f32x4;

typedef __attribute__((address_space(3))) void lds_void;
typedef const __attribute__((address_space(1))) void glb_void;
#define GLD16(g, l) __builtin_amdgcn_global_load_lds((glb_void*)(g), (lds_void*)(l), 16, 0, 0)

__device__ __forceinline__ u16 f2bf(float f) {
    u32 u = __float_as_uint(f);
    u = (u + 0x7FFFu + ((u >> 16) & 1u)) >> 16;
    return (u16)u;
}

// ---- elementwise fp32 -> bf16 cast (K fixed = 1024 columns) ----------------
__global__ void cast_k(const float* __restrict__ src, int ld, int off, int relu,
                       u16* __restrict__ dst, int n) {
    for (int i = blockIdx.x * blockDim.x + threadIdx.x; i < n; i += gridDim.x * blockDim.x) {
        int row = i >> 10, col = i & 1023;
        float v = src[(long)row * ld + off + col];
        if (relu) v = fmaxf(v, 0.f);
        dst[i] = f2bf(v);
    }
}

// ---- small fp32 GEMM: C[b][n] = z[b]·W[n, off:off+128] + bias[n] ----------
__global__ void smallgemm_k(const float* __restrict__ z, const float* __restrict__ W,
                            int ldw, int off, const float* __restrict__ bias,
                            float* __restrict__ C, u16* __restrict__ Cbf, int N) {
    int n = blockIdx.x;
    int b = threadIdx.x;
    float acc = bias[n];
    const float* zr = z + b * Ii;
    const float* wr = W + (long)n * ldw + off;
#pragma unroll 8
    for (int k = 0; k < Ii; ++k) acc += zr[k] * wr[k];
    C[b * N + n] = acc;
    if (Cbf) Cbf[b * N + n] = f2bf(acc);
}

// ---- E table GEMM: E[v][n] = relu(embed)[v]·Wihh[n]  (M=1024,N=3072,K=1024)
__global__ __launch_bounds__(256) void egemm_k(const u16* __restrict__ A,
                                               const u16* __restrict__ W,
                                               float* __restrict__ C) {
    __shared__ __align__(16) u16 lds[2][160 * 64]; // rows 0..31 = A, 32..159 = W
    int tid = threadIdx.x, lane = tid & 63, wv = tid >> 6;
    int r0 = (blockIdx.x & 31) * 32;
    int n0 = (blockIdx.x >> 5) * 128;

    f32x4 acc[2][2];
#pragma unroll
    for (int m = 0; m < 2; ++m)
#pragma unroll
        for (int n = 0; n < 2; ++n) acc[m][n] = (f32x4){0.f, 0.f, 0.f, 0.f};

    auto stage = [&](int k0, int bufi) {
#pragma unroll
        for (int r = 0; r < 5; ++r) {
            int L = r * 256 + tid;
            int row = L >> 3;
            int c4 = (L & 7) ^ (row & 7);
            const u16* src = (row < 32)
                                 ? A + (long)(r0 + row) * 1024 + k0 + c4 * 8
                                 : W + (long)(n0 + row - 32) * 1024 + k0 + c4 * 8;
            GLD16(src, &lds[bufi][L * 8]);
        }
    };
    stage(0, 0);
    stage(64, 1);
    for (int it = 0; it < 16; ++it) {
        if (it < 15) asm volatile("s_waitcnt vmcnt(5)" ::: "memory");
        else         asm volatile("s_waitcnt vmcnt(0)" ::: "memory");
        __builtin_amdgcn_s_barrier();
        const char* base = (const char*)&lds[it & 1][0];
        bf16x8 af[2][2], bfr[2][2];
#pragma unroll
        for (int ks = 0; ks < 2; ++ks)
#pragma unroll
            for (int q = 0; q < 2; ++q) {
                int kb = ks * 64 + ((lane >> 4) << 4);
                int rowa = q * 16 + (lane & 15);
                af[ks][q] = *(const bf16x8*)(base + rowa * 128 + (kb ^ ((rowa & 7) << 4)));
                int rowb = 32 + wv * 32 + q * 16 + (lane & 15);
                bfr[ks][q] = *(const bf16x8*)(base + rowb * 128 + (kb ^ ((rowb & 7) << 4)));
            }
#pragma unroll
        for (int ks = 0; ks < 2; ++ks)
#pragma unroll
            for (int m = 0; m < 2; ++m)
#pragma unroll
                for (int n = 0; n < 2; ++n)
                    acc[m][n] = __builtin_amdgcn_mfma_f32_16x16x32_bf16(af[ks][m], bfr[ks][n],
                                                                        acc[m][n], 0, 0, 0);
        asm volatile("s_waitcnt lgkmcnt(0)" ::: "memory");
        __builtin_amdgcn_s_barrier();
        if (it + 2 < 16) stage((it + 2) * 64, it & 1);
    }
#pragma unroll
    for (int m = 0; m < 2; ++m)
#pragma unroll
        for (int n = 0; n < 2; ++n)
#pragma unroll
            for (int r = 0; r < 4; ++r) {
                int row = r0 + m * 16 + ((lane >> 4) << 2) + r;
                int col = n0 + wv * 32 + n * 16 + (lane & 15);
                C[(long)row * 3072 + col] = acc[m][n][r];
            }
}

// ---- fused per-step kernel, grid 256 --------------------------------------
// blocks 0..127: GRU (h_{t-1} -> h_t), 32 rows x (3 gates x 64 j)
// blocks 128..255: OUT (h_{t-1} -> o_{t-1}), 32 rows x 64 v
__global__ __launch_bounds__(256) void step_k(
    const u16* __restrict__ Whh,   // [3072][1024] bf16
    const u16* __restrict__ Wout,  // [1024][1024] bf16 (out_w[:, :H])
    const float* __restrict__ E,   // [1024][3072]
    const float* __restrict__ Zih, // [256][3072]
    const float* __restrict__ Zout,// [256][1024]
    const float* __restrict__ bhh, // [3072]
    const int* __restrict__ toks,  // [128][256]
    const float* __restrict__ hpf, const u16* __restrict__ hpb, // h_{t-1}
    float* __restrict__ hnf, u16* __restrict__ hnb,             // h_t
    float* __restrict__ out, int t) {
    // GRU: 224 rows (32 A + 192 W) x 128 k, double-buffered = 112 KB
    __shared__ __align__(16) u16 lds[2][224 * 128];
    int bid = blockIdx.x;
    int tid = threadIdx.x, lane = tid & 63, wv = tid >> 6;
    bool isgru = bid < 128;
    if (isgru && t == NSTEP) return;
    if (!isgru && t == 0) return;
    int sb = isgru ? bid : bid - 128;
    int r0 = (sb >> 4) * 32;  // batch-row tile (8 row tiles)
    int cb = (sb & 15) * 64;  // j / v tile (16 col tiles; stride-16 bids -> same XCD)

    if (isgru) {
        f32x4 acc[2][3]; // [m][gate]
#pragma unroll
        for (int m = 0; m < 2; ++m)
#pragma unroll
            for (int g = 0; g < 3; ++g) acc[m][g] = (f32x4){0.f, 0.f, 0.f, 0.f};

        auto stage = [&](int k0, int bufi) {
#pragma unroll
            for (int r = 0; r < 14; ++r) {
                int L = r * 256 + tid;         // 0..3583
                int row = L >> 4;              // 0..223
                int ck = (L & 15) ^ (row & 15);
                const u16* src;
                if (row < 32) src = hpb + (long)(r0 + row) * 1024 + k0 + ck * 8;
                else {
                    int wr = row - 32; // g*64 + jl
                    src = Whh + (long)((wr >> 6) * 1024 + cb + (wr & 63)) * 1024 + k0 + ck * 8;
                }
                GLD16(src, &lds[bufi][L * 8]);
            }
        };
        stage(0, 0);
        stage(BK, 1);
        for (int it = 0; it < KIT; ++it) {
            if (it < KIT - 1) asm volatile("s_waitcnt vmcnt(14)" ::: "memory");
            else              asm volatile("s_waitcnt vmcnt(0)" ::: "memory");
            __builtin_amdgcn_s_barrier();
            const char* base = (const char*)&lds[it & 1][0];
            bf16x8 af[4][2];
#pragma unroll
            for (int ks = 0; ks < 4; ++ks)
#pragma unroll
                for (int m = 0; m < 2; ++m) {
                    int row = m * 16 + (lane & 15);
                    int ch = ks * 4 + (lane >> 4);
                    af[ks][m] = *(const bf16x8*)(base + row * 256 + ((ch ^ (row & 15)) << 4));
                }
#pragma unroll
            for (int g = 0; g < 3; ++g)
#pragma unroll
                for (int ks = 0; ks < 4; ++ks) {
                    int row = 32 + g * 64 + wv * 16 + (lane & 15);
                    int ch = ks * 4 + (lane >> 4);
                    bf16x8 bfrag =
                        *(const bf16x8*)(base + row * 256 + ((ch ^ (row & 15)) << 4));
#pragma unroll
                    for (int m = 0; m < 2; ++m)
                        acc[m][g] = __builtin_amdgcn_mfma_f32_16x16x32_bf16(
                            af[ks][m], bfrag, acc[m][g], 0, 0, 0);
                }
            asm volatile("s_waitcnt lgkmcnt(0)" ::: "memory");
            __builtin_amdgcn_s_barrier();
            if (it + 2 < KIT) stage((it + 2) * BK, it & 1);
        }
        // gates epilogue -> h_t
#pragma unroll
        for (int m = 0; m < 2; ++m)
#pragma unroll
            for (int r = 0; r < 4; ++r) {
                int b = r0 + m * 16 + ((lane >> 4) << 2) + r;
                int j = cb + wv * 16 + (lane & 15);
                int tok = (t == 0) ? 0 : toks[(t - 1) * Bb + b];
                float gir = E[(long)tok * 3072 + j] + Zih[(long)b * 3072 + j];
                float giz = E[(long)tok * 3072 + 1024 + j] + Zih[(long)b * 3072 + 1024 + j];
                float gin = E[(long)tok * 3072 + 2048 + j] + Zih[(long)b * 3072 + 2048 + j];
                float ghr = acc[m][0][r] + bhh[j];
                float ghz = acc[m][1][r] + bhh[1024 + j];
                float ghn = acc[m][2][r] + bhh[2048 + j];
                float rg = 1.f / (1.f + expf(-(gir + ghr)));
                float zg = 1.f / (1.f + expf(-(giz + ghz)));
                float nn = tanhf(gin + rg * ghn);
                float hp = hpf[b * 1024 + j];
                float hv = (1.f - zg) * nn + zg * hp;
                hnf[b * 1024 + j] = hv;
                hnb[b * 1024 + j] = f2bf(hv);
            }
    } else {
        f32x4 acc[2]; // [m]
#pragma unroll
        for (int m = 0; m < 2; ++m) acc[m] = (f32x4){0.f, 0.f, 0.f, 0.f};

        auto stage = [&](int k0, int bufi) {
#pragma unroll
            for (int r = 0; r < 6; ++r) {
                int L = r * 256 + tid;         // 0..1535
                int row = L >> 4;              // 0..95
                int ck = (L & 15) ^ (row & 15);
                const u16* src = (row < 32)
                                     ? hpb + (long)(r0 + row) * 1024 + k0 + ck * 8
                                     : Wout + (long)(cb + row - 32) * 1024 + k0 + ck * 8;
                GLD16(src, &lds[bufi][L * 8]);
            }
        };
        stage(0, 0);
        stage(BK, 1);
        for (int it = 0; it < KIT; ++it) {
            if (it < KIT - 1) asm volatile("s_waitcnt vmcnt(6)" ::: "memory");
            else              asm volatile("s_waitcnt vmcnt(0)" ::: "memory");
            __builtin_amdgcn_s_barrier();
            const char* base = (const char*)&lds[it & 1][0];
            bf16x8 af[4][2];
#pragma unroll
            for (int ks = 0; ks < 4; ++ks)
#pragma unroll
                for (int m = 0; m < 2; ++m) {
                    int row = m * 16 + (lane & 15);
                    int ch = ks * 4 + (lane >> 4);
                    af[ks][m] = *(const bf16x8*)(base + row * 256 + ((ch ^ (row & 15)) << 4));
                }
#pragma unroll
            for (int ks = 0; ks < 4; ++ks) {
                int row = 32 + wv * 16 + (lane & 15);
                int ch = ks * 4 + (lane >> 4);
                bf16x8 bfrag = *(const bf16x8*)(base + row * 256 + ((ch ^ (row & 15)) << 4));
#pragma unroll
                for (int m = 0; m < 2; ++m)
                    acc[m] = __builtin_amdgcn_mfma_f32_16x16x32_bf16(af[ks][m], bfrag,
                                                                     acc[m], 0, 0, 0);
            }
            asm volatile("s_waitcnt lgkmcnt(0)" ::: "memory");
            __builtin_amdgcn_s_barrier();
            if (it + 2 < KIT) stage((it + 2) * BK, it & 1);
        }
#pragma unroll
        for (int m = 0; m < 2; ++m)
#pragma unroll
            for (int r = 0; r < 4; ++r) {
                int b = r0 + m * 16 + ((lane >> 4) << 2) + r;
                int v = cb + wv * 16 + (lane & 15);
                out[(long)b * (NSTEP * Vv) + (long)(t - 1) * Vv + v] =
                    acc[m][r] + Zout[b * 1024 + v];
            }
    }
}

extern "C" void kernel_launch(void* const* d_in, const int* in_sizes, int n_in,
                              void* d_out, int out_size, void* d_ws, size_t ws_size,
                              hipStream_t stream) {
    const float* z = (const float*)d_in[0];
    const int* toks = (const int*)d_in[1];
    const float* embed_w = (const float*)d_in[3];
    const float* z2h_w = (const float*)d_in[4];
    const float* z2h_b = (const float*)d_in[5];
    const float* w_ih = (const float*)d_in[6];
    const float* b_ih = (const float*)d_in[7];
    const float* w_hh = (const float*)d_in[8];
    const float* b_hh = (const float*)d_in[9];
    const float* out_w = (const float*)d_in[10];
    const float* out_b = (const float*)d_in[11];
    float* out = (float*)d_out;

    char* ws = (char*)d_ws;
    size_t off = 0;
    auto alloc = [&](size_t bytes) {
        char* p = ws + off;
        off += (bytes + 255) & ~(size_t)255;
        return p;
    };
    u16* Whh_bf = (u16*)alloc(3072ull * 1024 * 2);
    u16* Wout_bf = (u16*)alloc(1024ull * 1024 * 2);
    u16* Wihh_bf = (u16*)alloc(3072ull * 1024 * 2);
    u16* Emb_bf = (u16*)alloc(1024ull * 1024 * 2);
    float* E = (float*)alloc(1024ull * 3072 * 4);
    float* Zih = (float*)alloc(256ull * 3072 * 4);
    float* Zout = (float*)alloc(256ull * 1024 * 4);
    float* hf = (float*)alloc(2ull * 256 * 1024 * 4);
    u16* hb = (u16*)alloc(2ull * 256 * 1024 * 2);
    // total ws use ~36.7 MB

    cast_k<<<2048, 256, 0, stream>>>(w_hh, 1024, 0, 0, Whh_bf, 3072 * 1024);
    cast_k<<<2048, 256, 0, stream>>>(out_w, 1152, 0, 0, Wout_bf, 1024 * 1024);
    cast_k<<<2048, 256, 0, stream>>>(w_ih, 1152, 0, 0, Wihh_bf, 3072 * 1024);
    cast_k<<<1024, 256, 0, stream>>>(embed_w, 1024, 0, 1, Emb_bf, 1024 * 1024);
    smallgemm_k<<<1024, 256, 0, stream>>>(z, z2h_w, 128, 0, z2h_b, hf, hb, 1024);
    smallgemm_k<<<3072, 256, 0, stream>>>(z, w_ih, 1152, 1024, b_ih, Zih, nullptr, 3072);
    smallgemm_k<<<1024, 256, 0, stream>>>(z, out_w, 1152, 1024, out_b, Zout, nullptr, 1024);
    egemm_k<<<768, 256, 0, stream>>>(Emb_bf, Wihh_bf, E);

    for (int t = 0; t <= NSTEP; ++t) {
        int cur = t & 1;
        step_k<<<256, 256, 0, stream>>>(Whh_bf, Wout_bf, E, Zih, Zout, b_hh, toks,
                                        hf + (size_t)cur * 256 * 1024,
                                        hb + (size_t)cur * 256 * 1024,
                                        hf + (size_t)(cur ^ 1) * 256 * 1024,
                                        hb + (size_t)(cur ^ 1) * 256 * 1024, out, t);
    }
}